// Round 7
// baseline (824.129 us; speedup 1.0000x reference)
//
#include <hip/hip_runtime.h>
#include <hip/hip_bf16.h>

// Problem constants (fixed by reference setup_inputs)
#define N_ATOMS   100000
#define N_BONDS   200000
#define MAX_NB    6
#define HIDDEN    300
#define ATOM_FDIM 133
#define BOND_FDIM 147
#define N_MOLS    5000
#define APM       20      // atoms per mol

#define MB_ROWS (N_BONDS + 1)   // 200001
#define MA_ROWS (N_ATOMS + 1)   // 100001

#define CHUNKS_B 1280     // 16B chunks per k-block image: 4*320*8 bf16 = 20480 B
#define EPS      308      // epilogue LDS row stride in floats (300 cols + pad)
#define ROWP     65       // padded A-panel rows per qg (64 + 1)

typedef unsigned short bf16_t;
typedef __attribute__((ext_vector_type(8))) __bf16 bf16x8;   // MFMA A/B frag
typedef __attribute__((ext_vector_type(4))) float  float4v;  // MFMA C/D frag
typedef __attribute__((ext_vector_type(2))) unsigned int uint2v;  // 8B payload

template<int N> struct IC { static constexpr int value = N; };

__device__ __forceinline__ float bf2f(unsigned short u) {
    union { unsigned int i; float f; } x; x.i = ((unsigned int)u) << 16; return x.f;
}
__device__ __forceinline__ unsigned short f2bf(float f) {
    union { float f; unsigned int i; } x; x.f = f;
    unsigned int r = x.i + 0x7FFFu + ((x.i >> 16) & 1u);   // RNE (finite values)
    return (unsigned short)(r >> 16);
}
// bf16 pair packed in one u32: lo = bits<<16, hi = bits&0xffff0000
__device__ __forceinline__ float lo_f(unsigned int u) {
    union { unsigned int i; float f; } x; x.i = u << 16; return x.f;
}
__device__ __forceinline__ float hi_f(unsigned int u) {
    union { unsigned int i; float f; } x; x.i = u & 0xffff0000u; return x.f;
}

// Inline-asm 8B global load (r6-proven: batches, compiler can't sink).
// Discipline: manual s_waitcnt vmcnt(0)+sched_barrier before first use;
// compiler-tracked loads drained before the batch (via sync or consumption).
__device__ __forceinline__ void gload8(uint2v& d, const void* a) {
    asm volatile("global_load_dwordx2 %0, %1, off"
                 : "=v"(d) : "v"(a) : "memory");
}
#define VM_DRAIN() do {                                      \
    asm volatile("s_waitcnt vmcnt(0)" ::: "memory");         \
    __builtin_amdgcn_sched_barrier(0);                       \
} while (0)

// ===========================================================================
// Weight prep: W fp32 -> bf16 k-block images. Chunk c of block kb holds, for
// q=c/320, col=c%320: Wv[kb*32+q*8+j][col], j=0..7 (zero-padded).
// perm=0: Wv[k] = W[k] for k<K.
// perm=1 (MODE2 image): virtual K layout [f_atoms 0..132 | pad 133..135 |
//         amsg 136..435] -> Wv[k] = W[k] (k<133), 0 (133..135), W[k-3]
//         (136..435), 0 beyond. Matches the MODE2 A-panel layout.
// ===========================================================================
__global__ __launch_bounds__(256) void prep_w(
    const float* __restrict__ W, bf16_t* __restrict__ dst, int K,
    int total_chunks, int perm)
{
    int idx = blockIdx.x * 256 + threadIdx.x;
    if (idx >= total_chunks) return;
    int kb  = idx / CHUNKS_B;
    int c   = idx - kb * CHUNKS_B;
    int cq  = c / 320;
    int col = c - cq * 320;
    unsigned short v[8];
    #pragma unroll
    for (int j = 0; j < 8; ++j) {
        int k = kb * 32 + cq * 8 + j;
        int ksrc;
        if (perm) ksrc = (k < 133) ? k : ((k >= 136 && k < 436) ? k - 3 : -1);
        else      ksrc = (k < K) ? k : -1;
        float f = (ksrc >= 0 && col < HIDDEN) ? W[(size_t)ksrc * HIDDEN + col] : 0.f;
        v[j] = f2bf(f);
    }
    bf16_t* p = dst + (size_t)idx * 8;
    *(ushort4*)(p)     = make_ushort4(v[0], v[1], v[2], v[3]);
    *(ushort4*)(p + 4) = make_ushort4(v[4], v[5], v[6], v[7]);
}

// ===========================================================================
// Full-A-panel MFMA GEMM, r7 revision — SPLIT-K staging for residency:
//   r6 post-mortem: staging variants (branchy/select/fenced/asm-batched)
//   all give IDENTICAL 146us -> staging latency is NOT the limit. Bottom-up
//   costing shows no pipe >45%: the limit is the serial phase chain with
//   only 3 (MODE1) / 2 (MODE2) resident blocks/CU (LDS 41.6/58 KB).
//   Fix: stage+compute the K dimension in TWO halves sharing one half-size
//   LDS buffer: stage(h0) -> kloop(h0) -> stage(h1) -> kloop(h1) -> epi.
//   LDS: MODE1 20.8 KB, MODE2 29.1 KB -> 4 blocks/CU (wave-capped, 100%).
//   Finer phases + more blocks = more cross-block overlap on all pipes.
// Maps (verified r5/r6): A m=lane&15, k=q*8+j; B n=lane&15, k=q*8+j;
// C/D col=lane&15, row=q*4+reg.
// Block: 512 thr = 8 waves (2m x 4n); tile 64(m) x 320(n); wave 32m x 80n.
// MODE 0: A = f_bonds fp32 [M,147];            Y = relu(A@W)     (unsplit)
// MODE 1: A = amsg[b2a[r]] - cur[b2revb[r]];   Y = relu(addend + A@W)
// MODE 2: A = [f_atoms(133)+pad3 | amsg(300)]; Y = relu(A@W + bias)
// ===========================================================================
template<int MODE, int KB, int KH1>
__global__ __launch_bounds__(512, 4) void gemm_mfma(
    const float* __restrict__ Af,
    const bf16_t* __restrict__ Ab1, const bf16_t* __restrict__ Ab2,
    const int* __restrict__ b2a, const int* __restrict__ b2revb,
    const bf16_t* __restrict__ WB, const float* __restrict__ bias,
    const bf16_t* __restrict__ addend, bf16_t* __restrict__ Y,
    int M)
{
    const int S = HIDDEN;   // output row stride 300
    constexpr int KH2 = KB - KH1;
    constexpr int QH1 = KH1 * 4, QH2 = KH2 * 4;
    constexpr int QGM = (QH1 > QH2) ? QH1 : QH2;     // half-panel qg count
    constexpr int ASZ = QGM * ROWP * 16;             // half A-panel bytes
    constexpr int LDS_BYTES = (ASZ > 16 * EPS * 4) ? ASZ : 16 * EPS * 4;
    __shared__ __align__(16) char lds_pool[LDS_BYTES];
    bf16_t* As  = (bf16_t*)lds_pool;                 // [(ql*65+row)*8], ql local
    float*  epi = (float*)lds_pool;                  // epilogue reuse
    __shared__ int rowmap[128];                      // MODE1: b2a | b2revb

    const int tid  = threadIdx.x;
    const int lane = tid & 63;
    const int w    = tid >> 6;        // 0..7
    const int wm   = w >> 2;          // m-half (0/1): 32 rows
    const int wn   = w & 3;           // n-quarter (0..3): 80 cols
    const int lrow = lane & 15;
    const int q    = lane >> 4;       // quad 0..3
    const int bm   = blockIdx.x * 64;

    // ---- MODE1: cache the per-row gather indices -------------------------
    if (MODE == 1) {
        if (tid < 64) {
            int sr = bm + tid;
            rowmap[tid] = (sr < M) ? b2a[sr] : 0;          // row 0 is all-zero
        } else if (tid < 128) {
            int sr = bm + tid - 64;
            rowmap[tid] = (sr < M) ? b2revb[sr] : 0;
        }
        __syncthreads();   // also drains compiler vmcnt (b2a/b2revb loads)
    }

    const bf16_t* wptr = WB + (size_t)(q * 320 + wn * 80 + lrow) * 8;

    float4v acc[2][5];
    #pragma unroll
    for (int i = 0; i < 2; ++i)
        #pragma unroll
        for (int j = 0; j < 5; ++j) {
            float4v z = {0.f, 0.f, 0.f, 0.f};
            acc[i][j] = z;
        }

    // ---- staging of one K-half into the shared half-buffer ---------------
    // qg global = QG0 + ql; As slot indexed by LOCAL ql. Tail guards are
    // wave-uniform (tail counts are multiples of 64), so branches around the
    // asm loads cost nothing and avoid duplicate gathers.
    auto stage_half = [&](auto QG0c, auto QGHc) {
        constexpr int QG0 = decltype(QG0c)::value;
        constexpr int QGH = decltype(QGHc)::value;
        constexpr int TASKS = 64 * QGH;
        constexpr int NT = (TASKS + 511) / 512;
        #define ACT(tt) ((TASKS % 512 == 0) || ((tt) < TASKS))

        if constexpr (MODE == 1) {
            uint2v A0[NT], A1[NT], C0[NT], C1[NT];
            #pragma unroll
            for (int i = 0; i < NT; ++i) {
                int t = tid + i * 512;
                if (ACT(t)) {
                    int row = t / QGH, ql = t - row * QGH;
                    int k0 = (QG0 + ql) * 8;
                    const bf16_t* pa = Ab1 + (size_t)rowmap[row]      * S;
                    const bf16_t* pc = Ab2 + (size_t)rowmap[64 + row] * S;
                    gload8(A0[i], (k0 + 4 <= S) ? (const void*)(pa + k0)     : (const void*)Ab1);
                    gload8(A1[i], (k0 + 8 <= S) ? (const void*)(pa + k0 + 4) : (const void*)Ab1);
                    gload8(C0[i], (k0 + 4 <= S) ? (const void*)(pc + k0)     : (const void*)Ab1);
                    gload8(C1[i], (k0 + 8 <= S) ? (const void*)(pc + k0 + 4) : (const void*)Ab1);
                }
            }
            VM_DRAIN();
            #pragma unroll
            for (int i = 0; i < NT; ++i) {
                int t = tid + i * 512;
                if (ACT(t)) {
                    int row = t / QGH, ql = t - row * QGH;
                    unsigned short av[8];
                    av[0] = f2bf(lo_f(A0[i].x) - lo_f(C0[i].x));
                    av[1] = f2bf(hi_f(A0[i].x) - hi_f(C0[i].x));
                    av[2] = f2bf(lo_f(A0[i].y) - lo_f(C0[i].y));
                    av[3] = f2bf(hi_f(A0[i].y) - hi_f(C0[i].y));
                    av[4] = f2bf(lo_f(A1[i].x) - lo_f(C1[i].x));
                    av[5] = f2bf(hi_f(A1[i].x) - hi_f(C1[i].x));
                    av[6] = f2bf(lo_f(A1[i].y) - lo_f(C1[i].y));
                    av[7] = f2bf(hi_f(A1[i].y) - hi_f(C1[i].y));
                    bf16_t* dst = As + (size_t)(ql * ROWP + row) * 8;
                    *(ushort4*)(dst)     = make_ushort4(av[0], av[1], av[2], av[3]);
                    *(ushort4*)(dst + 4) = make_ushort4(av[4], av[5], av[6], av[7]);
                }
            }
        } else if constexpr (MODE == 0) {
            float F[NT][8];
            #pragma unroll
            for (int i = 0; i < NT; ++i) {
                int t = tid + i * 512;
                if (ACT(t)) {
                    int row = t / QGH, ql = t - row * QGH, k0 = (QG0 + ql) * 8;
                    int srow = bm + row;
                    int rbase = srow * BOND_FDIM;
                    #pragma unroll
                    for (int j = 0; j < 8; ++j) {
                        int k = k0 + j;
                        F[i][j] = Af[(srow < M && k < BOND_FDIM) ? rbase + k : 0];
                    }
                }
            }
            #pragma unroll
            for (int i = 0; i < NT; ++i) {
                int t = tid + i * 512;
                if (ACT(t)) {
                    int row = t / QGH, ql = t - row * QGH;
                    unsigned short av[8];
                    #pragma unroll
                    for (int j = 0; j < 8; ++j) av[j] = f2bf(F[i][j]);
                    bf16_t* dst = As + (size_t)(ql * ROWP + row) * 8;
                    *(ushort4*)(dst)     = make_ushort4(av[0], av[1], av[2], av[3]);
                    *(ushort4*)(dst + 4) = make_ushort4(av[4], av[5], av[6], av[7]);
                }
            }
        } else {   // MODE 2: regions [f_atoms k<136 | amsg k>=136], per half
            constexpr int NF = (QG0 >= 17) ? 0 : ((17 - QG0 < QGH) ? 17 - QG0 : QGH);
            constexpr int TB = QGH - NF;
            if constexpr (NF > 0) {
                constexpr int T1 = 64 * NF;
                constexpr int NT1 = (T1 + 511) / 512;
                float Ff[NT1][8];
                #pragma unroll
                for (int i = 0; i < NT1; ++i) {
                    int u = tid + i * 512;
                    if ((T1 % 512 == 0) || u < T1) {
                        int row = u / NF, f = u - row * NF, k0 = (QG0 + f) * 8;
                        int srow = bm + row;
                        int rbase = srow * ATOM_FDIM;
                        #pragma unroll
                        for (int j = 0; j < 8; ++j) {
                            int k = k0 + j;
                            Ff[i][j] = Af[(srow < M && k < ATOM_FDIM) ? rbase + k : 0];
                        }
                    }
                }
                #pragma unroll
                for (int i = 0; i < NT1; ++i) {
                    int u = tid + i * 512;
                    if ((T1 % 512 == 0) || u < T1) {
                        int row = u / NF, f = u - row * NF;
                        unsigned short av[8];
                        #pragma unroll
                        for (int j = 0; j < 8; ++j) av[j] = f2bf(Ff[i][j]);
                        bf16_t* dst = As + (size_t)(f * ROWP + row) * 8;
                        *(ushort4*)(dst)     = make_ushort4(av[0], av[1], av[2], av[3]);
                        *(ushort4*)(dst + 4) = make_ushort4(av[4], av[5], av[6], av[7]);
                    }
                }
            }
            if constexpr (TB > 0) {
                constexpr int T2 = 64 * TB;
                constexpr int NT2 = (T2 + 511) / 512;
                ushort4 U0[NT2], U1[NT2];
                #pragma unroll
                for (int i = 0; i < NT2; ++i) {
                    int u = tid + i * 512;
                    if ((T2 % 512 == 0) || u < T2) {
                        int row = u / TB, b = u - row * TB;
                        int off = (QG0 + NF + b) * 8 - 136;    // amsg col offset
                        int srow = bm + row;
                        const bf16_t* pm = Ab1 + (size_t)srow * S;
                        bool ok = (srow < M);
                        U0[i] = *(const ushort4*)((ok && off + 4 <= S) ? pm + off     : Ab1);
                        U1[i] = *(const ushort4*)((ok && off + 8 <= S) ? pm + off + 4 : Ab1);
                    }
                }
                #pragma unroll
                for (int i = 0; i < NT2; ++i) {
                    int u = tid + i * 512;
                    if ((T2 % 512 == 0) || u < T2) {
                        int row = u / TB, b = u - row * TB;
                        int ql = NF + b;
                        bf16_t* dst = As + (size_t)(ql * ROWP + row) * 8;
                        *(ushort4*)(dst)     = U0[i];          // raw bf16 passthrough
                        *(ushort4*)(dst + 4) = U1[i];
                    }
                }
            }
        }
        #undef ACT
    };

    // ---- k-loop over one half: A from LDS (local kb), B from global ------
    auto run_kloop = [&](auto KB0c, auto KB1c) {
        constexpr int KB0 = decltype(KB0c)::value;
        constexpr int KB1 = decltype(KB1c)::value;
        bf16x8 bcur[5], bnxt[5];
        const bf16_t* w0 = wptr + (size_t)KB0 * (CHUNKS_B * 8);
        #pragma unroll
        for (int nt = 0; nt < 5; ++nt)
            bcur[nt] = *(const bf16x8*)(w0 + nt * 128);
        #pragma unroll
        for (int kb = KB0; kb < KB1; ++kb) {
            const bf16_t* abase = As + (size_t)(((kb - KB0) * 4 + q) * ROWP + wm * 32 + lrow) * 8;
            bf16x8 af0 = *(const bf16x8*)(abase);
            bf16x8 af1 = *(const bf16x8*)(abase + 16 * 8);   // +16 rows
            if (kb + 1 < KB1) {
                const bf16_t* wnx = wptr + (size_t)(kb + 1) * (CHUNKS_B * 8);
                #pragma unroll
                for (int nt = 0; nt < 5; ++nt)
                    bnxt[nt] = *(const bf16x8*)(wnx + nt * 128);
            }
            #pragma unroll
            for (int nt = 0; nt < 5; ++nt) {
                if (wn * 80 + nt * 16 < HIDDEN) {   // skip all-pad tile (304+)
                    acc[0][nt] = __builtin_amdgcn_mfma_f32_16x16x32_bf16(af0, bcur[nt], acc[0][nt], 0, 0, 0);
                    acc[1][nt] = __builtin_amdgcn_mfma_f32_16x16x32_bf16(af1, bcur[nt], acc[1][nt], 0, 0, 0);
                }
            }
            if (kb + 1 < KB1) {
                #pragma unroll
                for (int nt = 0; nt < 5; ++nt) bcur[nt] = bnxt[nt];
            }
        }
    };

    // ---- phase chain: stage(h0) -> kloop(h0) [-> stage(h1) -> kloop(h1)] -
    stage_half(IC<0>{}, IC<QH1>{});
    __syncthreads();                 // half-0 panel visible
    run_kloop(IC<0>{}, IC<KH1>{});
    if constexpr (KH2 > 0) {
        __syncthreads();             // all waves done reading half-0
        stage_half(IC<QH1>{}, IC<QH2>{});
        __syncthreads();             // half-1 panel visible
        run_kloop(IC<KH1>{}, IC<KB>{});
    }

    // ---- epilogue: LDS transpose -> coalesced ushort4 rows ---------------
    __syncthreads();   // safe to overwrite As pool
    #pragma unroll
    for (int mt = 0; mt < 2; ++mt) {
        for (int wh = 0; wh < 2; ++wh) {
            if (wm == wh) {
                #pragma unroll
                for (int nt = 0; nt < 5; ++nt) {
                    const int c0 = wn * 80 + nt * 16;
                    if (c0 < HIDDEN) {
                        #pragma unroll
                        for (int r = 0; r < 4; ++r)
                            epi[(q * 4 + r) * EPS + c0 + lrow] = acc[mt][nt][r];
                    }
                }
            }
            __syncthreads();
            const int row0 = bm + wh * 32 + mt * 16;
            for (int s = tid; s < 16 * 75; s += 512) {
                int rr = s / 75;
                int c4 = s - rr * 75;
                int grow = row0 + rr;
                if (grow < M) {
                    float4 v = *(const float4*)&epi[rr * EPS + c4 * 4];
                    if (MODE == 1) {
                        ushort4 ad = *(const ushort4*)(addend + (size_t)grow * S + c4 * 4);
                        v.x += bf2f(ad.x); v.y += bf2f(ad.y);
                        v.z += bf2f(ad.z); v.w += bf2f(ad.w);
                    }
                    if (MODE == 2) {
                        float4 bv = *(const float4*)(bias + c4 * 4);
                        v.x += bv.x; v.y += bv.y; v.z += bv.z; v.w += bv.w;
                    }
                    ushort4 o;
                    o.x = f2bf(v.x > 0.f ? v.x : 0.f);
                    o.y = f2bf(v.y > 0.f ? v.y : 0.f);
                    o.z = f2bf(v.z > 0.f ? v.z : 0.f);
                    o.w = f2bf(v.w > 0.f ? v.w : 0.f);
                    *(ushort4*)(Y + (size_t)grow * S + c4 * 4) = o;
                }
            }
            __syncthreads();   // before next stage overwrites epi
        }
    }
}

// ===========================================================================
// aggregate: amsg[a][:] = sum_j msg[a2b[a][j]][:]  (bf16, fp32 accumulate)
// r6-proven: 36 inline-asm row gathers in flight behind one vmcnt(0).
// ===========================================================================
__global__ __launch_bounds__(256, 4) void aggregate_k(
    const bf16_t* __restrict__ msg, const int* __restrict__ a2b,
    bf16_t* __restrict__ amsg)
{
    constexpr int TOT  = MA_ROWS * 25;       // 2,500,025 col-group tasks
    constexpr int HALF = (TOT + 1) / 2;      // 1,250,013
    int i0 = blockIdx.x * 256 + threadIdx.x;
    if (i0 >= HALF) return;
    int  i1   = i0 + HALF;
    bool has1 = (i1 < TOT);
    int  i1c  = has1 ? i1 : 0;               // clamp: atom 0 rows are zero
    int a0 = i0 / 25,  g0 = i0 - a0 * 25,  c0 = g0 * 12;
    int a1 = i1c / 25, g1 = i1c - a1 * 25, c1 = g1 * 12;

    const int* nb0 = a2b + (size_t)a0 * MAX_NB;
    const int* nb1 = a2b + (size_t)a1 * MAX_NB;
    int b0[MAX_NB], b1[MAX_NB];
    #pragma unroll
    for (int j = 0; j < MAX_NB; ++j) { b0[j] = nb0[j]; b1[j] = nb1[j]; }
    // drain compiler's own index loads before the asm batch (counter model)
    int chk = 0;
    #pragma unroll
    for (int j = 0; j < MAX_NB; ++j) chk |= b0[j] | b1[j];
    asm volatile("" :: "v"(chk));
    __builtin_amdgcn_sched_barrier(0);

    uint2v R0[MAX_NB][3], R1[MAX_NB][3];
    #pragma unroll
    for (int j = 0; j < MAX_NB; ++j) {
        const bf16_t* p = msg + (size_t)b0[j] * HIDDEN + c0;
        gload8(R0[j][0], p);
        gload8(R0[j][1], p + 4);
        gload8(R0[j][2], p + 8);
    }
    #pragma unroll
    for (int j = 0; j < MAX_NB; ++j) {
        const bf16_t* p = msg + (size_t)b1[j] * HIDDEN + c1;
        gload8(R1[j][0], p);
        gload8(R1[j][1], p + 4);
        gload8(R1[j][2], p + 8);
    }
    VM_DRAIN();   // 36 loads in flight -> one latency round

    float s0[12], s1[12];
    #pragma unroll
    for (int k = 0; k < 12; ++k) { s0[k] = 0.f; s1[k] = 0.f; }
    #pragma unroll
    for (int j = 0; j < MAX_NB; ++j) {
        #pragma unroll
        for (int h = 0; h < 3; ++h) {
            s0[h*4+0] += lo_f(R0[j][h].x); s0[h*4+1] += hi_f(R0[j][h].x);
            s0[h*4+2] += lo_f(R0[j][h].y); s0[h*4+3] += hi_f(R0[j][h].y);
            s1[h*4+0] += lo_f(R1[j][h].x); s1[h*4+1] += hi_f(R1[j][h].x);
            s1[h*4+2] += lo_f(R1[j][h].y); s1[h*4+3] += hi_f(R1[j][h].y);
        }
    }
    bf16_t* o0 = amsg + (size_t)a0 * HIDDEN + c0;
    *(ushort4*)(o0)     = make_ushort4(f2bf(s0[0]), f2bf(s0[1]), f2bf(s0[2]),  f2bf(s0[3]));
    *(ushort4*)(o0 + 4) = make_ushort4(f2bf(s0[4]), f2bf(s0[5]), f2bf(s0[6]),  f2bf(s0[7]));
    *(ushort4*)(o0 + 8) = make_ushort4(f2bf(s0[8]), f2bf(s0[9]), f2bf(s0[10]), f2bf(s0[11]));
    if (has1) {
        bf16_t* o1 = amsg + (size_t)a1 * HIDDEN + c1;
        *(ushort4*)(o1)     = make_ushort4(f2bf(s1[0]), f2bf(s1[1]), f2bf(s1[2]),  f2bf(s1[3]));
        *(ushort4*)(o1 + 4) = make_ushort4(f2bf(s1[4]), f2bf(s1[5]), f2bf(s1[6]),  f2bf(s1[7]));
        *(ushort4*)(o1 + 8) = make_ushort4(f2bf(s1[8]), f2bf(s1[9]), f2bf(s1[10]), f2bf(s1[11]));
    }
}

// mol_vecs[m][:] = mean over 20 consecutive atom rows (offset by 1), fp32 out
__global__ __launch_bounds__(256) void mol_mean_k(
    const bf16_t* __restrict__ atom_h, float* __restrict__ out)
{
    int idx = blockIdx.x * blockDim.x + threadIdx.x;
    if (idx >= N_MOLS * 75) return;
    int m  = idx / 75;
    int c4 = idx - m * 75;
    const bf16_t* base = atom_h + (size_t)(1 + m * APM) * HIDDEN + c4 * 4;
    float4 s = make_float4(0.f, 0.f, 0.f, 0.f);
    #pragma unroll
    for (int i = 0; i < APM; ++i) {
        ushort4 u = *(const ushort4*)(base + (size_t)i * HIDDEN);
        s.x += bf2f(u.x); s.y += bf2f(u.y); s.z += bf2f(u.z); s.w += bf2f(u.w);
    }
    const float inv = 1.0f / (float)APM;
    s.x *= inv; s.y *= inv; s.z *= inv; s.w *= inv;
    *(float4*)(out + (size_t)m * HIDDEN + c4 * 4) = s;
}

// ---------------------------------------------------------------------------
extern "C" void kernel_launch(void* const* d_in, const int* in_sizes, int n_in,
                              void* d_out, int out_size, void* d_ws, size_t ws_size,
                              hipStream_t stream)
{
    const float* f_atoms = (const float*)d_in[0];
    const float* f_bonds = (const float*)d_in[1];
    const float* W_i     = (const float*)d_in[2];
    const float* W_h     = (const float*)d_in[3];
    const float* W_o     = (const float*)d_in[4];
    const float* b_o     = (const float*)d_in[5];
    const int*   a2b     = (const int*)d_in[6];
    const int*   b2a     = (const int*)d_in[7];
    const int*   b2revb  = (const int*)d_in[8];
    float* out = (float*)d_out;

    // Workspace: r2/r5/r6-proven layout (300,002,136 B — do NOT grow d_ws!)
    char* base = (char*)d_ws;
    const size_t SZ_BOND_B = (((size_t)MB_ROWS * HIDDEN * sizeof(bf16_t)) + 255) & ~(size_t)255;
    bf16_t* inp  = (bf16_t*)(base);
    bf16_t* msgA = (bf16_t*)(base + SZ_BOND_B);
    bf16_t* amsg = (bf16_t*)(base + 2 * SZ_BOND_B);

    // Pre-blocked bf16 weights live in d_out scratch (6 MB; 593,920 B used).
    // Safe: fully consumed before mol_mean_k overwrites every output element.
    char* scratch = (char*)d_out;
    bf16_t* Wib = (bf16_t*)(scratch);                 //  5 kb * 20480 B = 102,400
    bf16_t* Whb = (bf16_t*)(scratch + 102400);        // 10 kb           = 204,800
    bf16_t* Wob = (bf16_t*)(scratch + 307200);        // 14 kb           = 286,720

    dim3 blk512(512), blk256(256);
    const int gb = (MB_ROWS + 63) / 64;   // 3126
    const int ga = (MA_ROWS + 63) / 64;   // 1563
    const int agg_tasks  = ((MA_ROWS * 25) + 1) / 2;  // 1,250,013 (2 per thread)
    int agg_blocks  = (agg_tasks + 255) / 256;
    int mean_blocks = (N_MOLS * 75 + 255) / 256;

    // 0) weight prep (tiny)
    prep_w<<<(5  * CHUNKS_B + 255) / 256, blk256, 0, stream>>>(W_i, Wib, BOND_FDIM, 5 * CHUNKS_B, 0);
    prep_w<<<(10 * CHUNKS_B + 255) / 256, blk256, 0, stream>>>(W_h, Whb, HIDDEN, 10 * CHUNKS_B, 0);
    prep_w<<<(14 * CHUNKS_B + 255) / 256, blk256, 0, stream>>>(W_o, Wob, 436, 14 * CHUNKS_B, 1);

    // 1) inp = relu(f_bonds @ W_i)   (unsplit: KH1 = KB = 5)
    gemm_mfma<0, 5, 5><<<gb, blk512, 0, stream>>>(
        f_bonds, nullptr, nullptr, nullptr, nullptr,
        Wib, nullptr, nullptr, inp, MB_ROWS);

    // 2) round 0: msgA = relu(inp + (agg -> gather-sub) @ W_h)   (5+5 split)
    aggregate_k<<<agg_blocks, blk256, 0, stream>>>(inp, a2b, amsg);
    gemm_mfma<1, 10, 5><<<gb, blk512, 0, stream>>>(
        nullptr, amsg, inp, b2a, b2revb,
        Whb, nullptr, inp, msgA, MB_ROWS);

    // 3) round 1: inp = relu(inp + ...) in-place (same-element alias only)
    aggregate_k<<<agg_blocks, blk256, 0, stream>>>(msgA, a2b, amsg);
    gemm_mfma<1, 10, 5><<<gb, blk512, 0, stream>>>(
        nullptr, amsg, msgA, b2a, b2revb,
        Whb, nullptr, inp, inp, MB_ROWS);

    // 4) readout: atom_h (=msgA) = relu([f_atoms | agg(inp)] @ W_o + b_o)  (7+7)
    aggregate_k<<<agg_blocks, blk256, 0, stream>>>(inp, a2b, amsg);
    gemm_mfma<2, 14, 7><<<ga, blk512, 0, stream>>>(
        f_atoms, amsg, nullptr, nullptr, nullptr,
        Wob, b_o, nullptr, msgA, MA_ROWS);

    // 5) per-molecule mean
    mol_mean_k<<<mean_blocks, blk256, 0, stream>>>(msgA, out);
}